// Round 10
// baseline (44.931 us; speedup 1.0000x reference)
//
#include <hip/hip_runtime.h>

#define FF 4096      // faces
#define IC 32        // i-chunk per block (staged in LDS)
#define BJ 256       // j per block (one per thread)
#define NBX (FF / BJ)          // 16 j-slabs
#define NBY (FF / IC)          // 128 i-chunks
#define NBLK (NBX * NBY)       // 2048 blocks
#define GRP 64                 // blocks per ticket group
#define NGRP (NBLK / GRP)      // 32 groups
#define CNT_STRIDE 32          // dwords between group counters (128B apart)
#define MCNT_IDX 1023          // master counter dword index

// ws layout (bytes):
//   [0,8192)        : counters, zeroed by memset node each call
//                     gcnt[g] at dword g*32, mcnt at dword 1023
//   [8192,16384)    : partial[2048] f32
//   [16384,16512)   : gsum[32] f32
// ---------------------------------------------------------------------------
// Single compute node. Pairs phase = R6 (proven 16.6us): one j per thread in
// registers, 32 i-records in LDS, broadcast reads. Completion: two-level
// ticket; the last arriver at each level does the reduction (NO waiting —
// R8/R9 showed waiting schemes cost +14..+50us). Reduction order is
// lane-indexed and fixed -> bitwise deterministic. Agent-scope atomics
// (per-XCD L2s not coherent for plain accesses).
// Diagonal i==j needs no test (S==0 up to fp noise; R6/R7 absmax 0.0).
// ---------------------------------------------------------------------------
__global__ __launch_bounds__(256, 8) void tcl_all(
    const float* __restrict__ verts,    // [V,3] f32
    const int* __restrict__ faces,      // [F,3] i32
    const float* __restrict__ probs,    // [F]   f32
    unsigned int* __restrict__ cnt,     // counters (zeroed each call)
    float* __restrict__ partial,        // [NBLK]
    float* __restrict__ gsum,           // [NGRP]
    float* __restrict__ d_out)
{
    __shared__ float4 s_n[IC];          // (nx,ny,nz,ref_dot)
    __shared__ float4 s_cp[IC];         // (cx,cy,cz,prob)
    __shared__ float s_red[4];

    const int tid = threadIdx.x;
    const int bx = blockIdx.x;
    const int j = (bx & (NBX - 1)) * BJ + tid;
    const int ibase = (bx >> 4) * IC;

    // ---- own j-face (registers) ----
    float t0x, t0y, t0z, t1x, t1y, t1z, t2x, t2y, t2z, cjx, cjy, cjz;
    {
        int a = faces[3 * j + 0];
        int b = faces[3 * j + 1];
        int c = faces[3 * j + 2];
        t0x = verts[3 * a]; t0y = verts[3 * a + 1]; t0z = verts[3 * a + 2];
        t1x = verts[3 * b]; t1y = verts[3 * b + 1]; t1z = verts[3 * b + 2];
        t2x = verts[3 * c]; t2y = verts[3 * c + 1]; t2z = verts[3 * c + 2];
        cjx = (t0x + t1x + t2x) * (1.0f / 3.0f);
        cjy = (t0y + t1y + t2y) * (1.0f / 3.0f);
        cjz = (t0z + t1z + t2z) * (1.0f / 3.0f);
    }

    // ---- i-chunk records into LDS (threads 0..IC-1) ----
    if (tid < IC) {
        int i = ibase + tid;
        int a = faces[3 * i + 0];
        int b = faces[3 * i + 1];
        int c = faces[3 * i + 2];
        float p0x = verts[3 * a], p0y = verts[3 * a + 1], p0z = verts[3 * a + 2];
        float p1x = verts[3 * b], p1y = verts[3 * b + 1], p1z = verts[3 * b + 2];
        float p2x = verts[3 * c], p2y = verts[3 * c + 1], p2z = verts[3 * c + 2];

        float v1x = p1x - p0x, v1y = p1y - p0y, v1z = p1z - p0z;
        float v2x = p2x - p0x, v2y = p2y - p0y, v2z = p2z - p0z;
        float nx = v1y * v2z - v1z * v2y;
        float ny = v1z * v2x - v1x * v2z;
        float nz = v1x * v2y - v1y * v2x;
        float nrm = sqrtf(nx * nx + ny * ny + nz * nz);
        float inv = 1.0f / fmaxf(nrm, 1e-12f);
        nx *= inv; ny *= inv; nz *= inv;
        float rd = p0x * nx + p0y * ny + p0z * nz;

        s_n[tid] = make_float4(nx, ny, nz, rd);
        s_cp[tid] = make_float4((p0x + p1x + p2x) * (1.0f / 3.0f),
                                (p0y + p1y + p2y) * (1.0f / 3.0f),
                                (p0z + p1z + p2z) * (1.0f / 3.0f),
                                probs[i]);
    }
    __syncthreads();

    // ---- pair loop ----
    float acc = 0.0f;
    #pragma unroll 8
    for (int ii = 0; ii < IC; ++ii) {
        float4 nf = s_n[ii];                 // broadcast (conflict-free)
        float4 cp = s_cp[ii];

        float dx = cp.x - cjx;
        float dy = cp.y - cjy;
        float dz = cp.z - cjz;
        float d2m1 = fmaf(dx, dx, fmaf(dy, dy, fmaf(dz, dz, -1.0f)));

        float S0 = fmaf(t0x, nf.x, fmaf(t0y, nf.y, fmaf(t0z, nf.z, -nf.w)));
        float S1 = fmaf(t1x, nf.x, fmaf(t1y, nf.y, fmaf(t1z, nf.z, -nf.w)));
        float S2 = fmaf(t2x, nf.x, fmaf(t2y, nf.y, fmaf(t2z, nf.z, -nf.w)));

        // intersect && near <=> max(mn*mx, d2-1) < 0
        float mn = fminf(fminf(S0, S1), S2);   // v_min3_f32
        float mx = fmaxf(fmaxf(S0, S1), S2);   // v_max3_f32
        float t = fmaxf(mn * mx, d2m1);

        acc += (t < 0.0f) ? cp.w : 0.0f;       // prob[i]
    }

    // ---- per-block reduce ----
    #pragma unroll
    for (int off = 32; off > 0; off >>= 1)
        acc += __shfl_down(acc, off, 64);

    const int wave = tid >> 6;
    const int lane = tid & 63;
    if (lane == 0) s_red[wave] = acc;
    __syncthreads();
    if (wave != 0) return;                    // waves 1..3 done

    float bsum = (s_red[0] + s_red[1]) + (s_red[2] + s_red[3]);

    // ---- level 1 ticket: publish partial, last of 64 in group reduces ----
    const int g = bx >> 6;                    // 32 groups of 64 blocks
    int old = 0;
    if (lane == 0) {
        __hip_atomic_store(&partial[bx], bsum,
                           __ATOMIC_RELAXED, __HIP_MEMORY_SCOPE_AGENT);
        old = (int)__hip_atomic_fetch_add(&cnt[g * CNT_STRIDE], 1u,
                                          __ATOMIC_ACQ_REL,
                                          __HIP_MEMORY_SCOPE_AGENT);
    }
    old = __shfl(old, 0, 64);                 // wave-uniform
    if (old != GRP - 1) return;

    // group-last block: lane-parallel reduce of this group's 64 partials
    float gs = __hip_atomic_load(&partial[g * GRP + lane],
                                 __ATOMIC_RELAXED, __HIP_MEMORY_SCOPE_AGENT);
    #pragma unroll
    for (int off = 32; off > 0; off >>= 1)
        gs += __shfl_down(gs, off, 64);

    // ---- level 2 ticket: publish group sum, last of 32 writes d_out ----
    int mold = 0;
    if (lane == 0) {
        __hip_atomic_store(&gsum[g], gs,
                           __ATOMIC_RELAXED, __HIP_MEMORY_SCOPE_AGENT);
        mold = (int)__hip_atomic_fetch_add(&cnt[MCNT_IDX], 1u,
                                           __ATOMIC_ACQ_REL,
                                           __HIP_MEMORY_SCOPE_AGENT);
    }
    mold = __shfl(mold, 0, 64);
    if (mold != NGRP - 1) return;

    float ms = (lane < NGRP)
        ? __hip_atomic_load(&gsum[lane],
                            __ATOMIC_RELAXED, __HIP_MEMORY_SCOPE_AGENT)
        : 0.0f;
    #pragma unroll
    for (int off = 32; off > 0; off >>= 1)
        ms += __shfl_down(ms, off, 64);

    if (lane == 0) d_out[0] = ms * (1.0f / (float)FF);
}

// ---------------------------------------------------------------------------
extern "C" void kernel_launch(void* const* d_in, const int* in_sizes, int n_in,
                              void* d_out, int out_size, void* d_ws, size_t ws_size,
                              hipStream_t stream)
{
    const float* verts = (const float*)d_in[0];   // [2048,3] f32
    const int* faces   = (const int*)d_in[1];     // [4096,3] int32
    const float* probs = (const float*)d_in[2];   // [4096] f32
    float* out = (float*)d_out;

    unsigned int* cnt = (unsigned int*)d_ws;            // [0,8192) counters
    float* partial = (float*)((char*)d_ws + 8192);      // [2048] f32
    float* gsum    = (float*)((char*)d_ws + 16384);     // [32] f32

    // re-zero counters every call (graph-capturable memset node; poison-proof)
    hipMemsetAsync(d_ws, 0, 8192, stream);

    tcl_all<<<dim3(NBLK), dim3(BJ), 0, stream>>>(verts, faces, probs,
                                                 cnt, partial, gsum, out);
}

// Round 11
// 17.940 us; speedup vs baseline: 2.5045x; 2.5045x over previous
//
#include <hip/hip_runtime.h>

typedef __attribute__((ext_vector_type(2))) float f32x2;

#define FF 4096      // faces
#define IC 32        // i-chunk per block (staged in LDS)
#define JR 2         // j-faces per thread (packed into f32x2 lanes)
#define BJT 256      // threads per block
#define BJ (BJT * JR)          // 512 j per block
#define NBX (FF / BJ)          // 8   j-slabs
#define NBY (FF / IC)          // 128 i-chunks
#define NPART (NBX * NBY)      // 1024 partials

// ---------------------------------------------------------------------------
// K1: fused pair kernel (R6 structure, proven 16.6us; JR=2 f32x2-packed).
// Each thread owns j0 = bx*512+tid and j1 = j0+256; the two j-faces' vertex
// coords live as f32x2 registers so S-plane dots and d2 compute as
// v_pk_fma_f32 (2 pairs per instruction). Threads 0..31 build the block's
// i-chunk records (normal, ref_dot, centroid, prob) in LDS; broadcast reads.
// No cross-block sync of any kind (R8/R9/R10: all in-node sync schemes cost
// +14..+50us on gfx950 — two plain nodes is the floor structure).
// Diagonal i==j needs no test (S==0 up to fp noise; R6/R7 absmax 0.0).
// ---------------------------------------------------------------------------
__global__ __launch_bounds__(256, 8) void tcl_pairs(
    const float* __restrict__ verts,    // [V,3] f32
    const int* __restrict__ faces,      // [F,3] i32
    const float* __restrict__ probs,    // [F]   f32
    float* __restrict__ partial)
{
    __shared__ float4 s_n[IC];          // (nx,ny,nz,ref_dot)
    __shared__ float4 s_cp[IC];         // (cx,cy,cz,prob)
    __shared__ float s_red[4];

    const int tid = threadIdx.x;
    const int jbase = blockIdx.x * BJ + tid;    // j's: jbase, jbase+256
    const int ibase = blockIdx.y * IC;

    // ---- own j-faces, packed: lane .x = j0, lane .y = j1 ----
    f32x2 ax2, ay2, az2, bx2, by2, bz2, cx2, cy2, cz2, ex2, ey2, ez2;
    {
        float t[2][9];
        #pragma unroll
        for (int k = 0; k < JR; ++k) {
            int j = jbase + k * BJT;
            int a = faces[3 * j + 0];
            int b = faces[3 * j + 1];
            int c = faces[3 * j + 2];
            t[k][0] = verts[3 * a]; t[k][1] = verts[3 * a + 1]; t[k][2] = verts[3 * a + 2];
            t[k][3] = verts[3 * b]; t[k][4] = verts[3 * b + 1]; t[k][5] = verts[3 * b + 2];
            t[k][6] = verts[3 * c]; t[k][7] = verts[3 * c + 1]; t[k][8] = verts[3 * c + 2];
        }
        ax2 = (f32x2){t[0][0], t[1][0]}; ay2 = (f32x2){t[0][1], t[1][1]}; az2 = (f32x2){t[0][2], t[1][2]};
        bx2 = (f32x2){t[0][3], t[1][3]}; by2 = (f32x2){t[0][4], t[1][4]}; bz2 = (f32x2){t[0][5], t[1][5]};
        cx2 = (f32x2){t[0][6], t[1][6]}; cy2 = (f32x2){t[0][7], t[1][7]}; cz2 = (f32x2){t[0][8], t[1][8]};
        ex2 = (ax2 + bx2 + cx2) * (1.0f / 3.0f);
        ey2 = (ay2 + by2 + cy2) * (1.0f / 3.0f);
        ez2 = (az2 + bz2 + cz2) * (1.0f / 3.0f);
    }

    // ---- i-chunk records into LDS (threads 0..IC-1) ----
    if (tid < IC) {
        int i = ibase + tid;
        int a = faces[3 * i + 0];
        int b = faces[3 * i + 1];
        int c = faces[3 * i + 2];
        float p0x = verts[3 * a], p0y = verts[3 * a + 1], p0z = verts[3 * a + 2];
        float p1x = verts[3 * b], p1y = verts[3 * b + 1], p1z = verts[3 * b + 2];
        float p2x = verts[3 * c], p2y = verts[3 * c + 1], p2z = verts[3 * c + 2];

        float v1x = p1x - p0x, v1y = p1y - p0y, v1z = p1z - p0z;
        float v2x = p2x - p0x, v2y = p2y - p0y, v2z = p2z - p0z;
        float nx = v1y * v2z - v1z * v2y;
        float ny = v1z * v2x - v1x * v2z;
        float nz = v1x * v2y - v1y * v2x;
        float nrm = sqrtf(nx * nx + ny * ny + nz * nz);
        float inv = 1.0f / fmaxf(nrm, 1e-12f);
        nx *= inv; ny *= inv; nz *= inv;
        float rd = p0x * nx + p0y * ny + p0z * nz;

        s_n[tid] = make_float4(nx, ny, nz, rd);
        s_cp[tid] = make_float4((p0x + p1x + p2x) * (1.0f / 3.0f),
                                (p0y + p1y + p2y) * (1.0f / 3.0f),
                                (p0z + p1z + p2z) * (1.0f / 3.0f),
                                probs[i]);
    }
    __syncthreads();

    // ---- pair loop: each iter tests i against both packed j's ----
    float acc0 = 0.0f, acc1 = 0.0f;
    #pragma unroll 8
    for (int ii = 0; ii < IC; ++ii) {
        float4 nf = s_n[ii];                 // broadcast (conflict-free)
        float4 cp = s_cp[ii];

        f32x2 mw = {-nf.w, -nf.w};
        f32x2 S0 = ax2 * nf.x + ay2 * nf.y + az2 * nf.z + mw;   // pk_fma x3
        f32x2 S1 = bx2 * nf.x + by2 * nf.y + bz2 * nf.z + mw;
        f32x2 S2 = cx2 * nf.x + cy2 * nf.y + cz2 * nf.z + mw;

        f32x2 dx = cp.x - ex2;
        f32x2 dy = cp.y - ey2;
        f32x2 dz = cp.z - ez2;
        f32x2 d2m1 = dx * dx + dy * dy + dz * dz - 1.0f;

        // intersect && near <=> max(mn*mx, d2-1) < 0
        float mn0 = fminf(fminf(S0.x, S1.x), S2.x);   // v_min3_f32
        float mx0 = fmaxf(fmaxf(S0.x, S1.x), S2.x);   // v_max3_f32
        float mn1 = fminf(fminf(S0.y, S1.y), S2.y);
        float mx1 = fmaxf(fmaxf(S0.y, S1.y), S2.y);
        float u0 = fmaxf(mn0 * mx0, d2m1.x);
        float u1 = fmaxf(mn1 * mx1, d2m1.y);

        acc0 += (u0 < 0.0f) ? cp.w : 0.0f;            // prob[i]
        acc1 += (u1 < 0.0f) ? cp.w : 0.0f;
    }
    float acc = acc0 + acc1;

    // ---- reduce: wave shuffle, cross-wave LDS, one store per block ----
    #pragma unroll
    for (int off = 32; off > 0; off >>= 1)
        acc += __shfl_down(acc, off, 64);

    int wave = tid >> 6;
    int lane = tid & 63;
    if (lane == 0) s_red[wave] = acc;
    __syncthreads();
    if (tid == 0)
        partial[blockIdx.y * NBX + blockIdx.x] =
            (s_red[0] + s_red[1]) + (s_red[2] + s_red[3]);
}

// ---------------------------------------------------------------------------
// K2: final reduce of 1024 partials -> d_out[0]. One block, 256 threads.
// ---------------------------------------------------------------------------
__global__ __launch_bounds__(256) void tcl_reduce(
    const float4* __restrict__ partial4,
    float* __restrict__ d_out)
{
    __shared__ float s_red[4];
    int tid = threadIdx.x;                 // 256 threads, NPART/4 = 256 float4
    float4 v = partial4[tid];
    float s = (v.x + v.y) + (v.z + v.w);

    #pragma unroll
    for (int off = 32; off > 0; off >>= 1)
        s += __shfl_down(s, off, 64);

    int wave = tid >> 6;
    int lane = tid & 63;
    if (lane == 0) s_red[wave] = s;
    __syncthreads();
    if (tid == 0) {
        float t = (s_red[0] + s_red[1]) + (s_red[2] + s_red[3]);
        d_out[0] = t * (1.0f / (float)FF);
    }
}

// ---------------------------------------------------------------------------
extern "C" void kernel_launch(void* const* d_in, const int* in_sizes, int n_in,
                              void* d_out, int out_size, void* d_ws, size_t ws_size,
                              hipStream_t stream)
{
    const float* verts = (const float*)d_in[0];   // [2048,3] f32
    const int* faces   = (const int*)d_in[1];     // [4096,3] int32
    const float* probs = (const float*)d_in[2];   // [4096] f32
    float* out = (float*)d_out;
    float* partial = (float*)d_ws;

    dim3 grid(NBX, NBY);                          // (8,128) = 1024 blocks
    tcl_pairs<<<grid, BJT, 0, stream>>>(verts, faces, probs, partial);

    tcl_reduce<<<1, 256, 0, stream>>>((const float4*)partial, out);
}

// Round 12
// 16.591 us; speedup vs baseline: 2.7082x; 1.0813x over previous
//
#include <hip/hip_runtime.h>

#define FF 4096      // faces
#define IC 32        // i-chunk per block (staged in LDS)
#define BJ 256       // j per block (one per thread)
#define NBX (FF / BJ)          // 16
#define NBY (FF / IC)          // 128
#define NPART (NBX * NBY)      // 2048 partials

// ---------------------------------------------------------------------------
// K1: fused pair kernel — R6 structure verbatim (best measured: 16.6us),
// inner loop tightened with the folded predicate (R7):
//   intersect && near  <=>  max(mn*mx, d2-1) < 0.
// One j per thread (vertices+centroid in registers, gathered from
// L1-resident verts/faces); threads 0..31 build the i-chunk records
// (normal, ref_dot, centroid, prob) in LDS; broadcast reads.
// grid (16,128) = 2048 blocks = 8 blocks/CU. Two plain nodes; all in-node
// cross-block sync schemes measured worse (R8 +50us, R9 +14us, R10 +28us).
// Diagonal i==j needs no test (S==0 up to fp noise; R6/R7/R11 absmax 0.0).
// ---------------------------------------------------------------------------
__global__ __launch_bounds__(256) void tcl_pairs(
    const float* __restrict__ verts,    // [V,3] f32
    const int* __restrict__ faces,      // [F,3] i32
    const float* __restrict__ probs,    // [F]   f32
    float* __restrict__ partial)
{
    __shared__ float4 s_n[IC];          // (nx,ny,nz,ref_dot)
    __shared__ float4 s_cp[IC];         // (cx,cy,cz,prob)
    __shared__ float s_red[4];

    const int tid = threadIdx.x;
    const int j = blockIdx.x * BJ + tid;
    const int ibase = blockIdx.y * IC;

    // ---- own j-face (registers) ----
    float t0x, t0y, t0z, t1x, t1y, t1z, t2x, t2y, t2z, cjx, cjy, cjz;
    {
        int a = faces[3 * j + 0];
        int b = faces[3 * j + 1];
        int c = faces[3 * j + 2];
        t0x = verts[3 * a]; t0y = verts[3 * a + 1]; t0z = verts[3 * a + 2];
        t1x = verts[3 * b]; t1y = verts[3 * b + 1]; t1z = verts[3 * b + 2];
        t2x = verts[3 * c]; t2y = verts[3 * c + 1]; t2z = verts[3 * c + 2];
        cjx = (t0x + t1x + t2x) * (1.0f / 3.0f);
        cjy = (t0y + t1y + t2y) * (1.0f / 3.0f);
        cjz = (t0z + t1z + t2z) * (1.0f / 3.0f);
    }

    // ---- i-chunk records into LDS (threads 0..IC-1) ----
    if (tid < IC) {
        int i = ibase + tid;
        int a = faces[3 * i + 0];
        int b = faces[3 * i + 1];
        int c = faces[3 * i + 2];
        float p0x = verts[3 * a], p0y = verts[3 * a + 1], p0z = verts[3 * a + 2];
        float p1x = verts[3 * b], p1y = verts[3 * b + 1], p1z = verts[3 * b + 2];
        float p2x = verts[3 * c], p2y = verts[3 * c + 1], p2z = verts[3 * c + 2];

        float v1x = p1x - p0x, v1y = p1y - p0y, v1z = p1z - p0z;
        float v2x = p2x - p0x, v2y = p2y - p0y, v2z = p2z - p0z;
        float nx = v1y * v2z - v1z * v2y;
        float ny = v1z * v2x - v1x * v2z;
        float nz = v1x * v2y - v1y * v2x;
        float nrm = sqrtf(nx * nx + ny * ny + nz * nz);
        float inv = 1.0f / fmaxf(nrm, 1e-12f);
        nx *= inv; ny *= inv; nz *= inv;
        float rd = p0x * nx + p0y * ny + p0z * nz;

        s_n[tid] = make_float4(nx, ny, nz, rd);
        s_cp[tid] = make_float4((p0x + p1x + p2x) * (1.0f / 3.0f),
                                (p0y + p1y + p2y) * (1.0f / 3.0f),
                                (p0z + p1z + p2z) * (1.0f / 3.0f),
                                probs[i]);
    }
    __syncthreads();

    // ---- pair loop ----
    float acc = 0.0f;
    #pragma unroll 8
    for (int ii = 0; ii < IC; ++ii) {
        float4 nf = s_n[ii];                 // broadcast (conflict-free)
        float4 cp = s_cp[ii];

        float dx = cp.x - cjx;
        float dy = cp.y - cjy;
        float dz = cp.z - cjz;
        float d2m1 = fmaf(dx, dx, fmaf(dy, dy, fmaf(dz, dz, -1.0f)));

        float S0 = fmaf(t0x, nf.x, fmaf(t0y, nf.y, fmaf(t0z, nf.z, -nf.w)));
        float S1 = fmaf(t1x, nf.x, fmaf(t1y, nf.y, fmaf(t1z, nf.z, -nf.w)));
        float S2 = fmaf(t2x, nf.x, fmaf(t2y, nf.y, fmaf(t2z, nf.z, -nf.w)));

        // intersect && near <=> max(mn*mx, d2-1) < 0
        float mn = fminf(fminf(S0, S1), S2);   // v_min3_f32
        float mx = fmaxf(fmaxf(S0, S1), S2);   // v_max3_f32
        float t = fmaxf(mn * mx, d2m1);

        acc += (t < 0.0f) ? cp.w : 0.0f;       // prob[i]
    }

    // ---- reduce: wave shuffle, cross-wave LDS, one store per block ----
    #pragma unroll
    for (int off = 32; off > 0; off >>= 1)
        acc += __shfl_down(acc, off, 64);

    int wave = tid >> 6;
    int lane = tid & 63;
    if (lane == 0) s_red[wave] = acc;
    __syncthreads();
    if (tid == 0)
        partial[blockIdx.y * NBX + blockIdx.x] =
            (s_red[0] + s_red[1]) + (s_red[2] + s_red[3]);
}

// ---------------------------------------------------------------------------
// K2: final reduce of 2048 partials -> d_out[0]. One block, 512 threads.
// ---------------------------------------------------------------------------
__global__ __launch_bounds__(512) void tcl_reduce(
    const float4* __restrict__ partial4,
    float* __restrict__ d_out)
{
    __shared__ float s_red[8];
    int tid = threadIdx.x;                 // 512 threads, NPART/4 = 512 float4
    float4 v = partial4[tid];
    float s = (v.x + v.y) + (v.z + v.w);

    #pragma unroll
    for (int off = 32; off > 0; off >>= 1)
        s += __shfl_down(s, off, 64);

    int wave = tid >> 6;
    int lane = tid & 63;
    if (lane == 0) s_red[wave] = s;
    __syncthreads();
    if (tid == 0) {
        float t = 0.0f;
        #pragma unroll
        for (int k = 0; k < 8; ++k) t += s_red[k];
        d_out[0] = t * (1.0f / (float)FF);
    }
}

// ---------------------------------------------------------------------------
extern "C" void kernel_launch(void* const* d_in, const int* in_sizes, int n_in,
                              void* d_out, int out_size, void* d_ws, size_t ws_size,
                              hipStream_t stream)
{
    const float* verts = (const float*)d_in[0];   // [2048,3] f32
    const int* faces   = (const int*)d_in[1];     // [4096,3] int32
    const float* probs = (const float*)d_in[2];   // [4096] f32
    float* out = (float*)d_out;
    float* partial = (float*)d_ws;

    dim3 grid(NBX, NBY);                          // (16,128) = 2048 blocks
    tcl_pairs<<<grid, BJ, 0, stream>>>(verts, faces, probs, partial);

    tcl_reduce<<<1, 512, 0, stream>>>((const float4*)partial, out);
}